// Round 11
// baseline (768.385 us; speedup 1.0000x reference)
//
#include <hip/hip_runtime.h>
#include <math.h>

// ---------------------------------------------------------------------------
// GCTLN round 11: single-pass decoupled-lookback Newton iterations.
//   k_coarse : serial fp32 RK4, dt=0.6 (1668 steps; was 0.45/375us)
//   k_start0 : interp seed -> 125k group-start states; zero lookback flags
//   k_iter x4: fused multiple-shooting iteration in ONE kernel:
//              walk-and-build 8 exact fp32 dopri5 steps (maps recorded) ->
//              register block scan -> publish aggregate -> decoupled
//              lookback (device-scope acquire/release) -> publish inclusive
//              -> fold -> new group-start states. No lpre round-trip.
//   k_polish : fp64 exact re-integration per group + fused readout.
// 7 launches total (r8: 17). Math of k_iter == r10's (validated, NITER=4).
// ---------------------------------------------------------------------------

#define C21 (1.0/5.0)
#define C31 (3.0/40.0)
#define C32 (9.0/40.0)
#define C41 (44.0/45.0)
#define C42 (-56.0/15.0)
#define C43 (32.0/9.0)
#define C51 (19372.0/6561.0)
#define C52 (-25360.0/2187.0)
#define C53 (64448.0/6561.0)
#define C54 (-212.0/729.0)
#define C61 (9017.0/3168.0)
#define C62 (-355.0/33.0)
#define C63 (46732.0/5247.0)
#define C64 (49.0/176.0)
#define C65 (-5103.0/18656.0)
#define B1  (35.0/384.0)
#define B3  (500.0/1113.0)
#define B4  (125.0/192.0)
#define B5  (-2187.0/6784.0)
#define B6  (11.0/84.0)

#define FT 256       // threads per block
#define FCH 8        // steps per thread (group)
#define NITER 4

struct MapF { float A[9]; float b[3]; };

__device__ inline void map_identity(MapF& m) {
#pragma unroll
  for (int i = 0; i < 9; ++i) m.A[i] = 0.f;
  m.A[0] = m.A[4] = m.A[8] = 1.f;
  m.b[0] = m.b[1] = m.b[2] = 0.f;
}

// out = m2 ∘ m1 (m1 applied first). out must not alias inputs.
__device__ inline void map_compose(MapF& out, const MapF& m2, const MapF& m1) {
#pragma unroll
  for (int r = 0; r < 3; ++r) {
#pragma unroll
    for (int c = 0; c < 3; ++c)
      out.A[r*3+c] = m2.A[r*3+0]*m1.A[0+c] + m2.A[r*3+1]*m1.A[3+c] + m2.A[r*3+2]*m1.A[6+c];
    out.b[r] = m2.A[r*3+0]*m1.b[0] + m2.A[r*3+1]*m1.b[1] + m2.A[r*3+2]*m1.b[2] + m2.b[r];
  }
}

__device__ inline void map_apply(const MapF& m, const float x[3], float y[3]) {
#pragma unroll
  for (int r = 0; r < 3; ++r)
    y[r] = m.A[r*3+0]*x[0] + m.A[r*3+1]*x[1] + m.A[r*3+2]*x[2] + m.b[r];
}

__device__ inline MapF map_shfl_up(const MapF& m, int off) {
  MapF r;
#pragma unroll
  for (int i = 0; i < 9; ++i) r.A[i] = __shfl_up(m.A[i], off, 64);
#pragma unroll
  for (int i = 0; i < 3; ++i) r.b[i] = __shfl_up(m.b[i], off, 64);
  return r;
}

template <typename T, bool RECORD>
__device__ inline void stage_k(const T z[3], const T th[3],
                               T wa, T wb, T g[3], T k[3]) {
  T y0 = fma(wa, z[2], fma(wb, z[1], th[0]));
  T y1 = fma(wa, z[0], fma(wb, z[2], th[1]));
  T y2 = fma(wa, z[1], fma(wb, z[0], th[2]));
  if (RECORD) {
    g[0] = (y0 > T(0)) ? T(1) : T(0);
    g[1] = (y1 > T(0)) ? T(1) : T(0);
    g[2] = (y2 > T(0)) ? T(1) : T(0);
  }
  k[0] = y0 * g[0] - z[0];
  k[1] = y1 * g[1] - z[1];
  k[2] = y2 * g[2] - z[2];
}

// RECORD=true: exact dopri5 step (gates from actual stage values).
template <typename T, bool RECORD>
__device__ inline void dopri_eval(const T v[3], const T th[3], T dt,
                                  T wa, T wb, T G[6][3], T out[3]) {
  T k1[3], k2[3], k3[3], k4[3], k5[3], k6[3], z[3];
  stage_k<T, RECORD>(v, th, wa, wb, G[0], k1);
  const T d21 = dt * T(C21);
#pragma unroll
  for (int c = 0; c < 3; ++c) z[c] = fma(d21, k1[c], v[c]);
  stage_k<T, RECORD>(z, th, wa, wb, G[1], k2);
#pragma unroll
  for (int c = 0; c < 3; ++c) z[c] = fma(dt, fma(T(C31), k1[c], T(C32) * k2[c]), v[c]);
  stage_k<T, RECORD>(z, th, wa, wb, G[2], k3);
#pragma unroll
  for (int c = 0; c < 3; ++c)
    z[c] = fma(dt, fma(T(C41), k1[c], fma(T(C42), k2[c], T(C43) * k3[c])), v[c]);
  stage_k<T, RECORD>(z, th, wa, wb, G[3], k4);
#pragma unroll
  for (int c = 0; c < 3; ++c)
    z[c] = fma(dt, fma(T(C51), k1[c], fma(T(C52), k2[c], fma(T(C53), k3[c], T(C54) * k4[c]))), v[c]);
  stage_k<T, RECORD>(z, th, wa, wb, G[4], k5);
#pragma unroll
  for (int c = 0; c < 3; ++c)
    z[c] = fma(dt, fma(T(C61), k1[c], fma(T(C62), k2[c], fma(T(C63), k3[c], fma(T(C64), k4[c], T(C65) * k5[c])))), v[c]);
  stage_k<T, RECORD>(z, th, wa, wb, G[5], k6);
#pragma unroll
  for (int c = 0; c < 3; ++c)
    out[c] = fma(dt, fma(T(B1), k1[c], fma(T(B3), k3[c], fma(T(B4), k4[c], fma(T(B5), k5[c], T(B6) * k6[c])))), v[c]);
}

// Build step map at x AND advance x by the exact nonlinear step.
__device__ inline void build_map_step(float x[3], float dt, float wa, float wb,
                                      const float th[3], MapF& m) {
  float G[6][3], xn[3];
  dopri_eval<float, true>(x, th, dt, wa, wb, G, xn);     // exact step + gates
  const float z3[3] = {0.f, 0.f, 0.f};
  dopri_eval<float, false>(z3, th, dt, wa, wb, G, m.b);  // b = F(0)
  float e[3], col[3];
#pragma unroll
  for (int j = 0; j < 3; ++j) {
    e[0] = 0.f; e[1] = 0.f; e[2] = 0.f; e[j] = 1.f;
    dopri_eval<float, false>(e, z3, dt, wa, wb, G, col); // A e_j (theta = 0)
    m.A[0 + j] = col[0];
    m.A[3 + j] = col[1];
    m.A[6 + j] = col[2];
  }
  x[0] = xn[0]; x[1] = xn[1]; x[2] = xn[2];
}

// In-block exclusive scan. P = exclusive prefix, tot = inclusive prefix.
__device__ inline void block_scan(MapF run, MapF& P, MapF& tot,
                                  MapF* wtot, int lane, int wid) {
#pragma unroll
  for (int off = 1; off < 64; off <<= 1) {
    MapF nb = map_shfl_up(run, off);
    MapF c; map_compose(c, run, nb);
    if (lane >= off) run = c;
  }
  if (lane == 63) wtot[wid] = run;
  __syncthreads();
  MapF wpre; map_identity(wpre);
  for (int w = 0; w < wid; ++w) { MapF t2; map_compose(t2, wtot[w], wpre); wpre = t2; }
  MapF excl = map_shfl_up(run, 1);
  if (lane == 0) map_identity(excl);
  map_compose(P, excl, wpre);
  map_compose(tot, run, wpre);
}

// load per-thread dts (clamped; padding steps get dt=0 -> identity maps)
__device__ inline void load_dtg(const float* __restrict__ t_eval, int n0, int T,
                                float dtg[FCH], float& tv0) {
  int i0 = n0 > T - 1 ? T - 1 : n0;
  tv0 = t_eval[i0];
  float prev = tv0;
#pragma unroll
  for (int s = 1; s <= FCH; ++s) {
    int idx = n0 + s; if (idx > T - 1) idx = T - 1;
    float c = t_eval[idx];
    dtg[s - 1] = c - prev;
    prev = c;
  }
}

// ----------------------------- kernels -------------------------------------

// sequential fp32 RK4 seed at fixed dtc (mask-guess quality only)
__global__ void k_coarse(const float* __restrict__ x0f,
                         const float* __restrict__ le, const float* __restrict__ ld,
                         const float* __restrict__ thf,
                         float* __restrict__ cst, int NC, float dtc) {
  if (threadIdx.x != 0 || blockIdx.x != 0) return;
  const float a = -1.f + expf(le[0]);
  const float b = -1.f - expf(ld[0]);
  const float t0 = thf[0], t1 = thf[1], t2 = thf[2];
  float x = x0f[0], y = x0f[1], z = x0f[2];
  cst[0] = x; cst[1] = y; cst[2] = z;
  const float dt = dtc, dth = 0.5f * dtc, dt6 = dtc * (1.f / 6.f);
#define RHSF(px, py, pz, kx, ky, kz)                      \
  do {                                                    \
    float y0_ = fmaf(a, (pz), fmaf(b, (py), t0));         \
    float y1_ = fmaf(a, (px), fmaf(b, (pz), t1));         \
    float y2_ = fmaf(a, (py), fmaf(b, (px), t2));         \
    (kx) = fmaxf(y0_, 0.f) - (px);                        \
    (ky) = fmaxf(y1_, 0.f) - (py);                        \
    (kz) = fmaxf(y2_, 0.f) - (pz);                        \
  } while (0)
  for (int i = 1; i <= NC; ++i) {
    float k1x,k1y,k1z,k2x,k2y,k2z,k3x,k3y,k3z,k4x,k4y,k4z,zx,zy,zz;
    RHSF(x, y, z, k1x, k1y, k1z);
    zx = fmaf(dth, k1x, x); zy = fmaf(dth, k1y, y); zz = fmaf(dth, k1z, z);
    RHSF(zx, zy, zz, k2x, k2y, k2z);
    zx = fmaf(dth, k2x, x); zy = fmaf(dth, k2y, y); zz = fmaf(dth, k2z, z);
    RHSF(zx, zy, zz, k3x, k3y, k3z);
    zx = fmaf(dt, k3x, x); zy = fmaf(dt, k3y, y); zz = fmaf(dt, k3z, z);
    RHSF(zx, zy, zz, k4x, k4y, k4z);
    x = fmaf(dt6, k1x + 2.f*k2x + 2.f*k3x + k4x, x);
    y = fmaf(dt6, k1y + 2.f*k2y + 2.f*k3y + k4y, y);
    z = fmaf(dt6, k1z + 2.f*k2z + 2.f*k3z + k4z, z);
    cst[3*i] = x; cst[3*i+1] = y; cst[3*i+2] = z;
  }
#undef RHSF
}

// interp seed onto group starts; zero the lookback flags
__global__ void k_start0(const float* __restrict__ t_eval,
                         const float* __restrict__ seedst,
                         const float* __restrict__ x0f,
                         float* __restrict__ gs, int* __restrict__ flags,
                         int nflags, int T, int NG1, float hseed, int nstates) {
  int g = blockIdx.x * blockDim.x + threadIdx.x;
  if (g < nflags) flags[g] = 0;
  if (g >= NG1) return;
  if (g == 0) { gs[0] = x0f[0]; gs[1] = x0f[1]; gs[2] = x0f[2]; return; }
  int n0 = g * FCH; if (n0 > T - 1) n0 = T - 1;
  float u = t_eval[n0] / hseed;
  int j = (int)u;
  if (j < 0) j = 0;
  if (j > nstates - 2) j = nstates - 2;
  float f = u - (float)j;
#pragma unroll
  for (int c = 0; c < 3; ++c) {
    float a0 = seedst[3*j + c], b0 = seedst[3*(j+1) + c];
    gs[3*g + c] = a0 + f * (b0 - a0);
  }
}

// one fused multiple-shooting iteration, decoupled-lookback global scan
__global__ __launch_bounds__(FT) void k_iter(
    const float* __restrict__ t_eval,
    const float* __restrict__ gs_in, float* __restrict__ gs_out,
    const float* __restrict__ x0f,
    const float* __restrict__ le, const float* __restrict__ ld,
    const float* __restrict__ thf,
    MapF* __restrict__ aggp, MapF* __restrict__ inclp, int* __restrict__ flags,
    int T, int NG1, int NB) {
  __shared__ MapF wtot[FT / 64];
  __shared__ MapF sAgg;
  __shared__ MapF sE;

  const int t = threadIdx.x, lane = t & 63, wid = t >> 6;
  const int bid = blockIdx.x;
  const int g = bid * FT + t;
  const bool active = (g < NG1);

  const float wa = -1.f + expf(le[0]);
  const float wb = -1.f - expf(ld[0]);
  const float th[3] = {thf[0], thf[1], thf[2]};
  const float x0d[3] = {x0f[0], x0f[1], x0f[2]};

  // walk-and-build this thread's group map (exact fp32 shooting from gs_in)
  MapF run;
  if (active) {
    float dtg[FCH]; float tv0;
    load_dtg(t_eval, g * FCH, T, dtg, tv0);
    float x[3] = {gs_in[3*g], gs_in[3*g+1], gs_in[3*g+2]};
    map_identity(run);
    MapF mp, tmp;
#pragma unroll
    for (int s = 0; s < FCH; ++s) {
      build_map_step(x, dtg[s], wa, wb, th, mp);
      map_compose(tmp, mp, run);
      run = tmp;
    }
  } else {
    map_identity(run);
  }

  MapF P, tot;
  block_scan(run, P, tot, wtot, lane, wid);

  // publish block aggregate
  if (t == FT - 1) {
    sAgg = tot;
    aggp[bid] = tot;
    __hip_atomic_store(&flags[bid], 1, __ATOMIC_RELEASE, __HIP_MEMORY_SCOPE_AGENT);
  }
  __syncthreads();

  // thread 0: decoupled lookback -> E (global exclusive block prefix)
  if (t == 0) {
    MapF E;
    if (bid == 0) {
      map_identity(E);
    } else {
      MapF A; map_identity(A);
      int j = bid - 1;
      while (true) {
        int f;
        do {
          f = __hip_atomic_load(&flags[j], __ATOMIC_ACQUIRE, __HIP_MEMORY_SCOPE_AGENT);
          if (f == 0) __builtin_amdgcn_s_sleep(1);
        } while (f == 0);
        if (f == 2) {
          MapF inc = inclp[j];
          MapF E2; map_compose(E2, A, inc);   // inc first (earlier in time)
          E = E2;
          break;
        } else {
          MapF ag = aggp[j];
          MapF A2; map_compose(A2, A, ag);    // ag first
          A = A2;
          --j;
          if (j < 0) { E = A; break; }        // unreachable: block0 posts incl
        }
      }
    }
    sE = E;
    MapF inc; map_compose(inc, sAgg, E);
    inclp[bid] = inc;
    __hip_atomic_store(&flags[bid], 2, __ATOMIC_RELEASE, __HIP_MEMORY_SCOPE_AGENT);
  }
  __syncthreads();

  // fold + write new group-start states
  if (active) {
    MapF E = sE;
    MapF Pg; map_compose(Pg, P, E);
    float ns[3]; map_apply(Pg, x0d, ns);
    if (g == 0) { ns[0] = x0d[0]; ns[1] = x0d[1]; ns[2] = x0d[2]; }
    gs_out[3*g]   = ns[0];
    gs_out[3*g+1] = ns[1];
    gs_out[3*g+2] = ns[2];
  }
}

// fp64 polish + fused readout
__global__ __launch_bounds__(256) void k_polish(
    const float* __restrict__ t_eval, const float* __restrict__ gstart,
    const float* __restrict__ x0f,
    const float* __restrict__ le, const float* __restrict__ ld,
    const float* __restrict__ thf,
    const float* __restrict__ row, const float* __restrict__ rob,
    float* __restrict__ traj, float* __restrict__ pred, int S, int T, int NG1) {
  const int g = blockIdx.x * blockDim.x + threadIdx.x;
  if (g >= NG1) return;
  const int n0 = g * FCH;
  float dtg[FCH]; float tv0;
  load_dtg(t_eval, n0, T, dtg, tv0);

  const double wa = -1.0 + exp((double)le[0]);
  const double wb = -1.0 - exp((double)ld[0]);
  const double th[3] = {(double)thf[0], (double)thf[1], (double)thf[2]};
  const float w00 = row[0], w01 = row[1], w02 = row[2];
  const float w10 = row[3], w11 = row[4], w12 = row[5];
  const float w20 = row[6], w21 = row[7], w22 = row[8];
  const float b0 = rob[0], b1 = rob[1], b2 = rob[2];

  double x[3];
  if (g == 0) {
    x[0] = (double)x0f[0]; x[1] = (double)x0f[1]; x[2] = (double)x0f[2];
    float a0 = x0f[0], a1 = x0f[1], a2 = x0f[2];
    traj[0] = a0; traj[1] = a1; traj[2] = a2;
    pred[0] = fmaf(w00, a0, fmaf(w01, a1, fmaf(w02, a2, b0)));
    pred[1] = fmaf(w10, a0, fmaf(w11, a1, fmaf(w12, a2, b1)));
    pred[2] = fmaf(w20, a0, fmaf(w21, a1, fmaf(w22, a2, b2)));
  } else {
    x[0] = (double)gstart[3*g]; x[1] = (double)gstart[3*g+1]; x[2] = (double)gstart[3*g+2];
  }

  double G[6][3], xn[3];
#pragma unroll
  for (int s = 0; s < FCH; ++s) {
    dopri_eval<double, true>(x, th, (double)dtg[s], wa, wb, G, xn);
    x[0] = xn[0]; x[1] = xn[1]; x[2] = xn[2];
    int n = n0 + s;
    if (n < S) {
      float a0 = (float)x[0], a1 = (float)x[1], a2 = (float)x[2];
      traj[3*(n+1)]   = a0;
      traj[3*(n+1)+1] = a1;
      traj[3*(n+1)+2] = a2;
      pred[3*(n+1)]   = fmaf(w00, a0, fmaf(w01, a1, fmaf(w02, a2, b0)));
      pred[3*(n+1)+1] = fmaf(w10, a0, fmaf(w11, a1, fmaf(w12, a2, b1)));
      pred[3*(n+1)+2] = fmaf(w20, a0, fmaf(w21, a1, fmaf(w22, a2, b2)));
    }
  }
}

// ----------------------------- launcher ------------------------------------

extern "C" void kernel_launch(void* const* d_in, const int* in_sizes, int n_in,
                              void* d_out, int out_size, void* d_ws, size_t ws_size,
                              hipStream_t stream) {
  const float* t_eval    = (const float*)d_in[0];
  const float* x0        = (const float*)d_in[1];
  const float* log_eps   = (const float*)d_in[2];
  const float* log_delta = (const float*)d_in[3];
  const float* theta     = (const float*)d_in[4];
  const float* readout_w = (const float*)d_in[5];
  const float* readout_b = (const float*)d_in[6];

  int T_   = in_sizes[0];
  int S_   = T_ - 1;
  int NG1_ = (S_ + FCH - 1) / FCH;              // 125000 groups
  int NB_  = (NG1_ + FT - 1) / FT;              // 489 blocks

  const float DTS_SEED = 0.6f;                  // RK4 |R(-2.08)| = 0.37, damped
  const int   NSEED    = (int)(((double)S_ * 1e-3) / (double)DTS_SEED) + 2;  // 1668
  int nstates_ = NSEED + 1;
  float hseed_ = DTS_SEED;

  float* trajh = (float*)d_out;
  float* predh = trajh + (size_t)3 * T_;

  char* w = (char*)d_ws;
  float* seedst = (float*)w;  w += (((size_t)3 * (NSEED + 1) * 4) + 255) & ~(size_t)255;
  float* gsA    = (float*)w;  w += (((size_t)3 * NG1_ * 4) + 255) & ~(size_t)255;
  float* gsB    = (float*)w;  w += (((size_t)3 * NG1_ * 4) + 255) & ~(size_t)255;
  MapF* aggp    = (MapF*)w;   w += (((size_t)NITER * NB_ * sizeof(MapF)) + 255) & ~(size_t)255;
  MapF* inclp   = (MapF*)w;   w += (((size_t)NITER * NB_ * sizeof(MapF)) + 255) & ~(size_t)255;
  int* flags    = (int*)w;    w += (((size_t)NITER * NB_ * 4) + 255) & ~(size_t)255;
  const int nflags = NITER * NB_;

  k_coarse<<<1, 64, 0, stream>>>(x0, log_eps, log_delta, theta, seedst, NSEED, DTS_SEED);
  k_start0<<<(NG1_ + 255) / 256, 256, 0, stream>>>(t_eval, seedst, x0, gsA, flags,
                                                   nflags, T_, NG1_, hseed_, nstates_);

  float* cur = gsA; float* nxt = gsB;
  for (int it = 0; it < NITER; ++it) {
    k_iter<<<NB_, FT, 0, stream>>>(t_eval, cur, nxt, x0, log_eps, log_delta, theta,
                                   aggp + (size_t)it * NB_,
                                   inclp + (size_t)it * NB_,
                                   flags + (size_t)it * NB_,
                                   T_, NG1_, NB_);
    float* tmp = cur; cur = nxt; nxt = tmp;
  }

  k_polish<<<(NG1_ + 255) / 256, 256, 0, stream>>>(t_eval, cur, x0,
                                                   log_eps, log_delta, theta,
                                                   readout_w, readout_b,
                                                   trajh, predh, S_, T_, NG1_);
}